// Round 2
// baseline (59550.641 us; speedup 1.0000x reference)
//
#include <hip/hip_runtime.h>
#include <math.h>

#define TT 256
#define BB 32
#define EE 256
#define HH 512
#define G4 2048
#define LL 9
#define NWG 256   // recurrence grid

typedef __attribute__((ext_vector_type(8))) __bf16 bf16x8;
typedef __attribute__((ext_vector_type(4))) float f32x4;

__device__ inline ushort f2bf(float f) {
  uint u = __float_as_uint(f);
  uint r = (u + 0x7fffu + ((u >> 16) & 1u)) >> 16;
  return (ushort)r;
}

// ---------------- embedding gather -> bf16, time-major (T*B, E) ----------------
__global__ __launch_bounds__(256) void embed_bf16(const int* __restrict__ ids,
                                                  const float* __restrict__ emb,
                                                  ushort* __restrict__ x0) {
  int idx = blockIdx.x * 256 + threadIdx.x;   // T*B*64 = 524288 exactly
  int e4 = idx & 63;
  int tb = idx >> 6;                          // t*32 + b
  int b = tb & 31, t = tb >> 5;
  int id = ids[b * TT + t];
  float4 v = *(const float4*)(emb + (size_t)id * EE + e4 * 4);
  ushort4 o;
  o.x = f2bf(v.x); o.y = f2bf(v.y); o.z = f2bf(v.z); o.w = f2bf(v.w);
  *(ushort4*)(x0 + (size_t)tb * EE + e4 * 4) = o;
}

// ---------------- fp32 -> bf16 weight conversion ----------------
__global__ __launch_bounds__(256) void conv_bf16(const float* __restrict__ in,
                                                 ushort* __restrict__ out, int n4) {
  int i = blockIdx.x * 256 + threadIdx.x;
  if (i >= n4) return;
  float4 v = *(const float4*)(in + (size_t)i * 4);
  ushort4 o;
  o.x = f2bf(v.x); o.y = f2bf(v.y); o.z = f2bf(v.z); o.w = f2bf(v.w);
  *(ushort4*)(out + (size_t)i * 4) = o;
}

// ---------------- bf16 MFMA pre-GEMM ----------------
// out[m][g] = sum_k A[m][k]*W[g][k] + bih[g] + bhh[g]
// A: (8192, K) bf16 row-major, W: (2048, K) bf16 row-major, out: (8192, 2048) fp32
// 128x128 tile, 4 waves (2x2), wave tile 64x64 = 4x4 frags of 16x16, BK=32.
// LDS tiles row-major [128][32] bf16, 16B-group XOR-swizzled by (row&3);
// staged with global_load_lds(16B) using pre-swizzled global source (rule #21).
template <int K>
__global__ __launch_bounds__(256) void pre_gemm_mfma(const ushort* __restrict__ A,
                                                     const ushort* __restrict__ W,
                                                     const float* __restrict__ bih,
                                                     const float* __restrict__ bhh,
                                                     float* __restrict__ out) {
  __shared__ ushort As[128 * 32];
  __shared__ ushort Ws[128 * 32];
  int tid = threadIdx.x;
  int lane = tid & 63, wid = tid >> 6;
  int m0 = blockIdx.x * 128, n0 = blockIdx.y * 128;
  int wm = (wid >> 1) * 64, wn = (wid & 1) * 64;

  f32x4 acc[4][4];
#pragma unroll
  for (int i = 0; i < 4; i++)
#pragma unroll
    for (int j = 0; j < 4; j++) acc[i][j] = (f32x4){0.f, 0.f, 0.f, 0.f};

  // staging chunk ids (16B chunks; 512 chunks per tile, 2 per thread per tile)
  int s1 = tid, s2 = tid + 256;
  int r1 = s1 >> 2, r2 = s2 >> 2;
  int g1 = (s1 & 3) ^ (r1 & 3);
  int g2 = (s2 & 3) ^ (r2 & 3);
  const ushort* a1 = A + (size_t)(m0 + r1) * K + g1 * 8;
  const ushort* a2 = A + (size_t)(m0 + r2) * K + g2 * 8;
  const ushort* w1 = W + (size_t)(n0 + r1) * K + g1 * 8;
  const ushort* w2 = W + (size_t)(n0 + r2) * K + g2 * 8;
  ushort* la1 = &As[(s1 & ~63) * 8];
  ushort* la2 = &As[(s2 & ~63) * 8];
  ushort* lw1 = &Ws[(s1 & ~63) * 8];
  ushort* lw2 = &Ws[(s2 & ~63) * 8];

  // frag read offsets (same XOR swizzle on the read side)
  int ra = (lane & 15), gl = lane >> 4;

  for (int k0 = 0; k0 < K; k0 += 32) {
    __builtin_amdgcn_global_load_lds(a1 + k0, la1, 16, 0, 0);
    __builtin_amdgcn_global_load_lds(a2 + k0, la2, 16, 0, 0);
    __builtin_amdgcn_global_load_lds(w1 + k0, lw1, 16, 0, 0);
    __builtin_amdgcn_global_load_lds(w2 + k0, lw2, 16, 0, 0);
    __syncthreads();   // drains vmcnt before barrier -> LDS tiles ready
    bf16x8 af[4], bfr[4];
#pragma unroll
    for (int f = 0; f < 4; f++) {
      int rowa = wm + f * 16 + ra;
      int ga = gl ^ (rowa & 3);
      af[f] = *(const bf16x8*)&As[rowa * 32 + ga * 8];
      int rowb = wn + f * 16 + ra;
      int gb = gl ^ (rowb & 3);
      bfr[f] = *(const bf16x8*)&Ws[rowb * 32 + gb * 8];
    }
#pragma unroll
    for (int i = 0; i < 4; i++)
#pragma unroll
      for (int j = 0; j < 4; j++)
        acc[i][j] = __builtin_amdgcn_mfma_f32_16x16x32_bf16(af[i], bfr[j], acc[i][j], 0, 0, 0);
    __syncthreads();
  }

  // epilogue: D lane map col = lane&15, row = (lane>>4)*4 + r  [m89-verified]
  int cl = lane & 15, rb4 = (lane >> 4) * 4;
#pragma unroll
  for (int j = 0; j < 4; j++) {
    int col = n0 + wn + j * 16 + cl;
    float bias = bih[col] + bhh[col];
#pragma unroll
    for (int i = 0; i < 4; i++) {
      int mb = m0 + wm + i * 16 + rb4;
#pragma unroll
      for (int r = 0; r < 4; r++)
        out[(size_t)(mb + r) * G4 + col] = acc[i][j][r] + bias;
    }
  }
}

// ---------------- persistent bidirectional LSTM layer ----------------
// 256 WGs x 512 threads. WG: dir = wg>>7, j0 = (wg&127)*4 (4 hidden units, 16 gate rows).
// W_hh slice (16x512 fp32) in LDS for the whole layer; c-state in LDS.
// Per step: 4-way K-split x 8 row-pairs x 16 b-pairs GEMV tiles, LDS reduce,
// activations by 128 threads, then device-scope grid barrier.
__global__ __launch_bounds__(512) void lstm_layer(
    const float* __restrict__ pre_f, const float* __restrict__ pre_r,
    const float* __restrict__ whh_f, const float* __restrict__ whh_r,
    float* __restrict__ h0buf, float* __restrict__ h1buf,
    float* __restrict__ xcat_f32, ushort* __restrict__ xcat_bf,
    int* ctr, int* flag) {
  __shared__ float ws[16][516];    // stride 516: 8 distinct bank groups for row-pairs
  __shared__ float gs[4][16][32];  // [ksplit][local gate row][b]
  __shared__ float cbuf[4][32];    // c state: [unit jj][b]

  int wg = blockIdx.x;
  int dir = wg >> 7;
  int j0 = (wg & 127) * 4;
  const float* whh = dir ? whh_r : whh_f;
  const float* pre = dir ? pre_r : pre_f;
  int tid = threadIdx.x;

  // load W slice: local row lr = q*4+jj -> whh row q*512 + j0 + jj
  for (int i = tid; i < 16 * 128; i += 512) {
    int lr = i >> 7;
    int k4 = (i & 127) * 4;
    int q = lr >> 2, jj = lr & 3;
    float4 v = *(const float4*)(whh + (size_t)(q * HH + j0 + jj) * HH + k4);
    *(float4*)&ws[lr][k4] = v;
  }
  if (tid < 128) cbuf[(tid >> 5) & 3][tid & 31] = 0.f;
  __syncthreads();

  int ks = tid >> 7;          // 0..3  K quarter
  int gi = (tid >> 4) & 7;    // 0..7  row pair
  int bi = tid & 15;          // 0..15 batch pair
  int lr0 = gi * 2;
  int ajj = (tid >> 5) & 3, ab = tid & 31;   // activation role (tid<128)
  const float* wr0 = &ws[lr0][ks * 128];
  const float* wr1 = &ws[lr0 + 1][ks * 128];

  for (int t = 0; t < TT; ++t) {
    int seq = dir ? (TT - 1 - t) : t;
    const float* hp = ((t & 1) ? h1buf : h0buf) + dir * (BB * HH);
    float* hn = ((t & 1) ? h0buf : h1buf) + dir * (BB * HH);

    // prefetch pre-activations for the epilogue (hides HBM latency under GEMV)
    float p_i = 0.f, p_f = 0.f, p_g = 0.f, p_o = 0.f;
    if (tid < 128) {
      size_t pb = ((size_t)seq * BB + ab) * G4 + j0 + ajj;
      p_i = pre[pb];
      p_f = pre[pb + HH];
      p_g = pre[pb + 2 * HH];
      p_o = pre[pb + 3 * HH];
    }

    const float* h0p = hp + (size_t)(2 * bi) * HH + ks * 128;
    const float* h1p = h0p + HH;
    float a00 = 0.f, a01 = 0.f, a10 = 0.f, a11 = 0.f;
#pragma unroll 4
    for (int k = 0; k < 128; k += 4) {
      float4 w0 = *(const float4*)(wr0 + k);
      float4 w1 = *(const float4*)(wr1 + k);
      float4 x0v = *(const float4*)(h0p + k);
      float4 x1v = *(const float4*)(h1p + k);
      a00 += w0.x * x0v.x + w0.y * x0v.y + w0.z * x0v.z + w0.w * x0v.w;
      a01 += w0.x * x1v.x + w0.y * x1v.y + w0.z * x1v.z + w0.w * x1v.w;
      a10 += w1.x * x0v.x + w1.y * x0v.y + w1.z * x0v.z + w1.w * x0v.w;
      a11 += w1.x * x1v.x + w1.y * x1v.y + w1.z * x1v.z + w1.w * x1v.w;
    }
    *(float2*)&gs[ks][lr0][2 * bi] = make_float2(a00, a01);
    *(float2*)&gs[ks][lr0 + 1][2 * bi] = make_float2(a10, a11);
    __syncthreads();

    if (tid < 128) {
      float gv_i = gs[0][0 + ajj][ab] + gs[1][0 + ajj][ab] + gs[2][0 + ajj][ab] + gs[3][0 + ajj][ab] + p_i;
      float gv_f = gs[0][4 + ajj][ab] + gs[1][4 + ajj][ab] + gs[2][4 + ajj][ab] + gs[3][4 + ajj][ab] + p_f;
      float gv_g = gs[0][8 + ajj][ab] + gs[1][8 + ajj][ab] + gs[2][8 + ajj][ab] + gs[3][8 + ajj][ab] + p_g;
      float gv_o = gs[0][12 + ajj][ab] + gs[1][12 + ajj][ab] + gs[2][12 + ajj][ab] + gs[3][12 + ajj][ab] + p_o;
      float si = 1.f / (1.f + expf(-gv_i));
      float sf = 1.f / (1.f + expf(-gv_f));
      float so = 1.f / (1.f + expf(-gv_o));
      float tg = tanhf(gv_g);
      float c = sf * cbuf[ajj][ab] + si * tg;
      cbuf[ajj][ab] = c;
      float h = so * tanhf(c);
      hn[(size_t)ab * HH + j0 + ajj] = h;
      size_t xb = ((size_t)seq * BB + ab) * 1024 + dir * HH + j0 + ajj;
      xcat_f32[xb] = h;
      xcat_bf[xb] = f2bf(h);
    }

    // ---- device-scope grid barrier (epoch t) ----
    __threadfence();
    __syncthreads();
    if (tid == 0) {
      int old = __hip_atomic_fetch_add(ctr, 1, __ATOMIC_ACQ_REL, __HIP_MEMORY_SCOPE_AGENT);
      if (old == t * NWG + (NWG - 1)) {
        __hip_atomic_store(flag, t + 1, __ATOMIC_RELEASE, __HIP_MEMORY_SCOPE_AGENT);
      } else {
        while (__hip_atomic_load(flag, __ATOMIC_ACQUIRE, __HIP_MEMORY_SCOPE_AGENT) <= t)
          __builtin_amdgcn_s_sleep(2);
      }
    }
    __syncthreads();
    __threadfence();
  }
}

// ---------------- classifier ----------------
__global__ __launch_bounds__(256) void cls_kernel(const float* __restrict__ x2,
                                                  const float* __restrict__ cw,
                                                  const float* __restrict__ cb,
                                                  float* __restrict__ em) {
  int idx = blockIdx.x * blockDim.x + threadIdx.x;
  if (idx >= BB * TT * LL) return;
  int l = idx % LL;
  int bt = idx / LL;
  int t = bt % TT;
  int b = bt / TT;
  const float4* xr = (const float4*)(x2 + ((size_t)t * BB + b) * 1024);
  const float4* wr = (const float4*)(cw + (size_t)l * 1024);
  float s = 0.f;
#pragma unroll 4
  for (int k = 0; k < 256; k++) {
    float4 xv = xr[k], wv = wr[k];
    s += xv.x * wv.x + xv.y * wv.y + xv.z * wv.z + xv.w * wv.w;
  }
  em[idx] = s + cb[l];
}

// ---------------- CRF NLL ----------------
__global__ __launch_bounds__(320) void crf_kernel(const float* __restrict__ em,
                                                  const int* __restrict__ labels,
                                                  const int* __restrict__ mask,
                                                  const float* __restrict__ start,
                                                  const float* __restrict__ end,
                                                  const float* __restrict__ trans,
                                                  float* __restrict__ loss_out) {
  __shared__ float al[32][9], tr[81], st[9], en[9];
  __shared__ float sc[32], red[32];
  __shared__ int pv[32];
  int tid = threadIdx.x;
  if (tid < 81) tr[tid] = trans[tid];
  if (tid < 9) { st[tid] = start[tid]; en[tid] = end[tid]; }
  __syncthreads();
  int j = tid >> 5, b = tid & 31;
  bool act = tid < 288;
  if (act) {
    int tg0 = labels[b * TT + 0];
    if (tg0 == -100) tg0 = 0;
    al[b][j] = st[j] + em[((size_t)b * TT + 0) * LL + j];
    if (j == 0) {
      sc[b] = st[tg0] + em[((size_t)b * TT + 0) * LL + tg0];
      pv[b] = tg0;
    }
  }
  __syncthreads();
  for (int t = 1; t < TT; t++) {
    float nxt = 0.f;
    int tg = 0;
    float mk = 0.f;
    if (act) {
      tg = labels[b * TT + t];
      if (tg == -100) tg = 0;
      mk = (float)mask[b * TT + t];
      float e_tj = em[((size_t)b * TT + t) * LL + j];
      float m = -1e30f;
#pragma unroll
      for (int i = 0; i < 9; i++) m = fmaxf(m, al[b][i] + tr[i * 9 + j]);
      float s = 0.f;
#pragma unroll
      for (int i = 0; i < 9; i++) s += expf(al[b][i] + tr[i * 9 + j] - m);
      nxt = m + logf(s) + e_tj;
    }
    __syncthreads();
    if (act) {
      if (j == 0 && mk > 0.f) {
        sc[b] += tr[pv[b] * 9 + tg] + em[((size_t)b * TT + t) * LL + tg];
      }
      if (mk > 0.f) al[b][j] = nxt;
      if (j == 0 && mk > 0.f) pv[b] = tg;
    }
    __syncthreads();
  }
  if (act && j == 0) {
    float m = -1e30f;
    for (int i = 0; i < 9; i++) m = fmaxf(m, al[b][i] + en[i]);
    float s = 0.f;
    for (int i = 0; i < 9; i++) s += expf(al[b][i] + en[i] - m);
    float logz = m + logf(s);
    red[b] = (sc[b] + en[pv[b]]) - logz;
  }
  __syncthreads();
  if (tid == 0) {
    float tot = 0.f;
    for (int bb = 0; bb < 32; bb++) tot += red[bb];
    loss_out[0] = -tot / 32.f;
  }
}

extern "C" void kernel_launch(void* const* d_in, const int* in_sizes, int n_in,
                              void* d_out, int out_size, void* d_ws, size_t ws_size,
                              hipStream_t stream) {
  (void)in_sizes; (void)n_in; (void)out_size; (void)ws_size;
  const int* ids = (const int*)d_in[0];
  const int* amask = (const int*)d_in[1];
  const int* labels = (const int*)d_in[2];
  const float* emb = (const float*)d_in[3];
  const float* wih0f = (const float*)d_in[4];
  const float* whh0f = (const float*)d_in[5];
  const float* bih0f = (const float*)d_in[6];
  const float* bhh0f = (const float*)d_in[7];
  const float* wih0r = (const float*)d_in[8];
  const float* whh0r = (const float*)d_in[9];
  const float* bih0r = (const float*)d_in[10];
  const float* bhh0r = (const float*)d_in[11];
  const float* wih1f = (const float*)d_in[12];
  const float* whh1f = (const float*)d_in[13];
  const float* bih1f = (const float*)d_in[14];
  const float* bhh1f = (const float*)d_in[15];
  const float* wih1r = (const float*)d_in[16];
  const float* whh1r = (const float*)d_in[17];
  const float* bih1r = (const float*)d_in[18];
  const float* bhh1r = (const float*)d_in[19];
  const float* cls_w = (const float*)d_in[20];
  const float* cls_b = (const float*)d_in[21];
  const float* crf_s = (const float*)d_in[22];
  const float* crf_e = (const float*)d_in[23];
  const float* crf_t = (const float*)d_in[24];

  float* ws = (float*)d_ws;
  int* ctr0 = (int*)ws;            // ws[0]
  int* flg0 = (int*)ws + 16;       // 64B apart
  int* ctr1 = (int*)ws + 32;
  int* flg1 = (int*)ws + 48;
  float* h_a = ws + 64;            // layer0 ping (zeroed)
  float* h_b = h_a + 32768;        // layer1 ping (zeroed)
  float* h_c = h_b + 32768;        // layer0 pong
  float* h_d = h_c + 32768;        // layer1 pong
  float* xc_f32 = h_d + 32768;     // (T*B,1024) fp32, shared by both layers
  float* pref = xc_f32 + 8388608;  // (T*B,2048)
  float* prer = pref + 16777216;
  ushort* x0bf = (ushort*)(prer + 16777216);  // (T*B,256) bf16
  ushort* xc_bf = x0bf + 2097152;             // (T*B,1024) bf16
  ushort* wb0f = xc_bf + 8388608;             // 2048*256
  ushort* wb0r = wb0f + 524288;
  ushort* wb1f = wb0r + 524288;               // 2048*1024
  ushort* wb1r = wb1f + 2097152;

  float* loss = (float*)d_out;
  float* em = (float*)d_out + 1;

  // zero barrier words + both ping h-buffers (contiguous: 256B + 2*128KB)
  hipMemsetAsync(ws, 0, 256 + 2 * 32768 * sizeof(float), stream);

  embed_bf16<<<2048, 256, 0, stream>>>(ids, emb, x0bf);
  conv_bf16<<<512, 256, 0, stream>>>(wih0f, wb0f, 131072);
  conv_bf16<<<512, 256, 0, stream>>>(wih0r, wb0r, 131072);
  conv_bf16<<<2048, 256, 0, stream>>>(wih1f, wb1f, 524288);
  conv_bf16<<<2048, 256, 0, stream>>>(wih1r, wb1r, 524288);

  // ---- layer 0 ----
  pre_gemm_mfma<256><<<dim3(64, 16), 256, 0, stream>>>(x0bf, wb0f, bih0f, bhh0f, pref);
  pre_gemm_mfma<256><<<dim3(64, 16), 256, 0, stream>>>(x0bf, wb0r, bih0r, bhh0r, prer);
  {
    const float* a0 = pref; const float* a1 = prer;
    const float* a2 = whh0f; const float* a3 = whh0r;
    float* a4 = h_a; float* a5 = h_c;
    float* a6 = xc_f32; ushort* a7 = xc_bf;
    int* a8 = ctr0; int* a9 = flg0;
    void* args[] = {&a0, &a1, &a2, &a3, &a4, &a5, &a6, &a7, &a8, &a9};
    hipLaunchCooperativeKernel((void*)lstm_layer, dim3(NWG), dim3(512), args, 0, stream);
  }
  // ---- layer 1 ----
  pre_gemm_mfma<1024><<<dim3(64, 16), 256, 0, stream>>>(xc_bf, wb1f, bih1f, bhh1f, pref);
  pre_gemm_mfma<1024><<<dim3(64, 16), 256, 0, stream>>>(xc_bf, wb1r, bih1r, bhh1r, prer);
  {
    const float* a0 = pref; const float* a1 = prer;
    const float* a2 = whh1f; const float* a3 = whh1r;
    float* a4 = h_b; float* a5 = h_d;
    float* a6 = xc_f32; ushort* a7 = xc_bf;
    int* a8 = ctr1; int* a9 = flg1;
    void* args[] = {&a0, &a1, &a2, &a3, &a4, &a5, &a6, &a7, &a8, &a9};
    hipLaunchCooperativeKernel((void*)lstm_layer, dim3(NWG), dim3(512), args, 0, stream);
  }

  cls_kernel<<<(BB * TT * LL + 255) / 256, 256, 0, stream>>>(xc_f32, cls_w, cls_b, em);
  crf_kernel<<<1, 320, 0, stream>>>(em, labels, amask, crf_s, crf_e, crf_t, loss);
}

// Round 3
// 5828.113 us; speedup vs baseline: 10.2178x; 10.2178x over previous
//
#include <hip/hip_runtime.h>
#include <math.h>

#define TT 256
#define BB 32
#define EE 256
#define HH 512
#define G4 2048
#define LL 9
#define NWGD 64   // workgroups per direction in the recurrence

typedef __attribute__((ext_vector_type(8))) __bf16 bf16x8;
typedef __attribute__((ext_vector_type(4))) float f32x4;

__device__ inline ushort f2bf(float f) {
  uint u = __float_as_uint(f);
  uint r = (u + 0x7fffu + ((u >> 16) & 1u)) >> 16;
  return (ushort)r;
}
__device__ inline float bf2f(uint lo16) { return __uint_as_float(lo16 << 16); }

// ---------------- embedding gather -> bf16, time-major (T*B, E) ----------------
__global__ __launch_bounds__(256) void embed_bf16(const int* __restrict__ ids,
                                                  const float* __restrict__ emb,
                                                  ushort* __restrict__ x0) {
  int idx = blockIdx.x * 256 + threadIdx.x;   // T*B*64 = 524288 exactly
  int e4 = idx & 63;
  int tb = idx >> 6;                          // t*32 + b
  int b = tb & 31, t = tb >> 5;
  int id = ids[b * TT + t];
  float4 v = *(const float4*)(emb + (size_t)id * EE + e4 * 4);
  ushort4 o;
  o.x = f2bf(v.x); o.y = f2bf(v.y); o.z = f2bf(v.z); o.w = f2bf(v.w);
  *(ushort4*)(x0 + (size_t)tb * EE + e4 * 4) = o;
}

// ---------------- W (2048 x K) fp32 -> bf16 with gate permutation ----------------
// out row' = unit*4 + gate  <-  in row = gate*512 + unit
template <int K>
__global__ __launch_bounds__(256) void conv_perm_bf16(const float* __restrict__ in,
                                                      ushort* __restrict__ out) {
  int idx = blockIdx.x * 256 + threadIdx.x;   // over 2048*K/4
  if (idx >= 2048 * (K / 4)) return;
  int rp = idx / (K / 4);
  int c4 = (idx % (K / 4)) * 4;
  int src = (rp & 3) * 512 + (rp >> 2);
  float4 v = *(const float4*)(in + (size_t)src * K + c4);
  ushort4 o;
  o.x = f2bf(v.x); o.y = f2bf(v.y); o.z = f2bf(v.z); o.w = f2bf(v.w);
  *(ushort4*)(out + (size_t)rp * K + c4) = o;
}

// ---------------- bf16 MFMA pre-GEMM (permuted gate columns) ----------------
// out[m][g'] = sum_k A[m][k]*W'[g'][k] + bih[orig(g')] + bhh[orig(g')]
template <int K>
__global__ __launch_bounds__(256) void pre_gemm_mfma(const ushort* __restrict__ A,
                                                     const ushort* __restrict__ W,
                                                     const float* __restrict__ bih,
                                                     const float* __restrict__ bhh,
                                                     float* __restrict__ out) {
  __shared__ ushort As[128 * 32];
  __shared__ ushort Ws[128 * 32];
  int tid = threadIdx.x;
  int lane = tid & 63, wid = tid >> 6;
  int m0 = blockIdx.x * 128, n0 = blockIdx.y * 128;
  int wm = (wid >> 1) * 64, wn = (wid & 1) * 64;

  f32x4 acc[4][4];
#pragma unroll
  for (int i = 0; i < 4; i++)
#pragma unroll
    for (int j = 0; j < 4; j++) acc[i][j] = (f32x4){0.f, 0.f, 0.f, 0.f};

  int s1 = tid, s2 = tid + 256;
  int r1 = s1 >> 2, r2 = s2 >> 2;
  int g1 = (s1 & 3) ^ (r1 & 3);
  int g2 = (s2 & 3) ^ (r2 & 3);
  const ushort* a1 = A + (size_t)(m0 + r1) * K + g1 * 8;
  const ushort* a2 = A + (size_t)(m0 + r2) * K + g2 * 8;
  const ushort* w1 = W + (size_t)(n0 + r1) * K + g1 * 8;
  const ushort* w2 = W + (size_t)(n0 + r2) * K + g2 * 8;
  ushort* la1 = &As[(s1 & ~63) * 8];
  ushort* la2 = &As[(s2 & ~63) * 8];
  ushort* lw1 = &Ws[(s1 & ~63) * 8];
  ushort* lw2 = &Ws[(s2 & ~63) * 8];

  int ra = (lane & 15), gl = lane >> 4;

  for (int k0 = 0; k0 < K; k0 += 32) {
    __builtin_amdgcn_global_load_lds(a1 + k0, la1, 16, 0, 0);
    __builtin_amdgcn_global_load_lds(a2 + k0, la2, 16, 0, 0);
    __builtin_amdgcn_global_load_lds(w1 + k0, lw1, 16, 0, 0);
    __builtin_amdgcn_global_load_lds(w2 + k0, lw2, 16, 0, 0);
    __syncthreads();
    bf16x8 af[4], bfr[4];
#pragma unroll
    for (int f = 0; f < 4; f++) {
      int rowa = wm + f * 16 + ra;
      int ga = gl ^ (rowa & 3);
      af[f] = *(const bf16x8*)&As[rowa * 32 + ga * 8];
      int rowb = wn + f * 16 + ra;
      int gb = gl ^ (rowb & 3);
      bfr[f] = *(const bf16x8*)&Ws[rowb * 32 + gb * 8];
    }
#pragma unroll
    for (int i = 0; i < 4; i++)
#pragma unroll
      for (int j = 0; j < 4; j++)
        acc[i][j] = __builtin_amdgcn_mfma_f32_16x16x32_bf16(af[i], bfr[j], acc[i][j], 0, 0, 0);
    __syncthreads();
  }

  int cl = lane & 15, rb4 = (lane >> 4) * 4;
#pragma unroll
  for (int j = 0; j < 4; j++) {
    int col = n0 + wn + j * 16 + cl;           // permuted gate index g'
    int orig = (col & 3) * 512 + (col >> 2);   // original gate row
    float bias = bih[orig] + bhh[orig];
#pragma unroll
    for (int i = 0; i < 4; i++) {
      int mb = m0 + wm + i * 16 + rb4;
#pragma unroll
      for (int r = 0; r < 4; r++)
        out[(size_t)(mb + r) * G4 + col] = acc[i][j][r] + bias;
    }
  }
}

// ---------------- persistent MFMA bidirectional LSTM layer ----------------
// 128 WGs x 256 thr. dir = wg>>6, wgl = wg&63 -> units [wgl*8, wgl*8+8), gate rows'
// [wgl*32, wgl*32+32). 4 waves = (batch-half mq) x (gate-half nq) quadrants of the
// 32x32 gate tile; K=512 in 16 MFMA k-steps. W'hh B-frags resident in VGPRs all layer.
// Grid barrier: relaxed polls (no cache inv), tid0-only release/acquire fences.
__global__ __launch_bounds__(256) void lstm_layer_mfma(
    const float* __restrict__ pre_f, const float* __restrict__ pre_r,
    const ushort* __restrict__ whhp_f, const ushort* __restrict__ whhp_r,
    ushort* __restrict__ hping, ushort* __restrict__ hpong,   // each [2][32][512] bf16
    ushort* __restrict__ xcat_bf,
    int* __restrict__ sync_base) {
  __shared__ float gs[32][33];
  int wg = blockIdx.x;
  int dir = wg >> 6;
  int wgl = wg & 63;
  const float* pre = dir ? pre_r : pre_f;
  const ushort* wp = dir ? whhp_r : whhp_f;
  int* ctr = sync_base + dir * 512;          // 2KB apart per dir
  int* flag = sync_base + 256 + dir * 512;   // 1KB from ctr

  int tid = threadIdx.x;
  int lane = tid & 63, wid = tid >> 6;
  int mq = wid & 1, nq = wid >> 1;
  int cl = lane & 15, gl = lane >> 4;

  // resident B-fragments: W'[row'][k], row' = wgl*32 + nq*16 + cl, k = kt*32 + gl*8
  bf16x8 bfrag[16];
  {
    const ushort* wrow = wp + (size_t)(wgl * 32 + nq * 16 + cl) * 512 + gl * 8;
#pragma unroll
    for (int kt = 0; kt < 16; kt++) bfrag[kt] = *(const bf16x8*)(wrow + kt * 32);
  }
  int u = tid >> 5, b = tid & 31;   // epilogue role: unit-local, batch
  int ug = wgl * 8 + u;             // global unit
  float creg = 0.f;                 // c-state lives in a register
  int ab = mq * 16 + cl;            // A-frag batch row

  for (int t = 0; t < TT; ++t) {
    int seq = dir ? (TT - 1 - t) : t;
    const ushort* hp = ((t & 1) ? hpong : hping) + dir * (32 * 512);
    ushort* hn = ((t & 1) ? hping : hpong) + dir * (32 * 512);

    // prefetch pre-activations (permuted layout: 4 consecutive = i,f,g,o of unit ug)
    float4 p4 = *(const float4*)(pre + ((size_t)seq * 32 + b) * G4 + ug * 4);

    // A-frags from global h (bf16), then 16 chained MFMAs
    f32x4 acc = (f32x4){0.f, 0.f, 0.f, 0.f};
    const ushort* arow = hp + (size_t)ab * 512 + gl * 8;
    bf16x8 afr[16];
#pragma unroll
    for (int kt = 0; kt < 16; kt++) afr[kt] = *(const bf16x8*)(arow + kt * 32);
#pragma unroll
    for (int kt = 0; kt < 16; kt++)
      acc = __builtin_amdgcn_mfma_f32_16x16x32_bf16(afr[kt], bfrag[kt], acc, 0, 0, 0);

    // dump quadrant to LDS: row = batch, col = local gate row'
    int rb = mq * 16 + gl * 4;
    int cc = nq * 16 + cl;
#pragma unroll
    for (int r = 0; r < 4; r++) gs[rb + r][cc] = acc[r];
    __syncthreads();

    // epilogue: thread (u,b) owns one (unit,batch)
    float gi_ = gs[b][4 * u + 0] + p4.x;
    float gf_ = gs[b][4 * u + 1] + p4.y;
    float gg_ = gs[b][4 * u + 2] + p4.z;
    float go_ = gs[b][4 * u + 3] + p4.w;
    float si = 1.f / (1.f + expf(-gi_));
    float sf = 1.f / (1.f + expf(-gf_));
    float so = 1.f / (1.f + expf(-go_));
    float tg = tanhf(gg_);
    creg = sf * creg + si * tg;
    float h = so * tanhf(creg);
    ushort h16 = f2bf(h);
    hn[b * 512 + ug] = h16;
    xcat_bf[((size_t)seq * 32 + b) * 1024 + dir * 512 + ug] = h16;

    __syncthreads();   // drains vmcnt: all h/xcat stores complete to L2
    if (tid == 0) {
      __threadfence();  // release: write back L2 to coherence point
      int old = __hip_atomic_fetch_add(ctr, 1, __ATOMIC_RELAXED, __HIP_MEMORY_SCOPE_AGENT);
      if (old == t * NWGD + (NWGD - 1)) {
        __hip_atomic_store(flag, t + 1, __ATOMIC_RELEASE, __HIP_MEMORY_SCOPE_AGENT);
      } else {
        int spin = 0;
        while (__hip_atomic_load(flag, __ATOMIC_RELAXED, __HIP_MEMORY_SCOPE_AGENT) <= t) {
          __builtin_amdgcn_s_sleep(4);
          if ((++spin & 1023) == 0)   // safety net: rare coherent poll
            (void)__hip_atomic_load(flag, __ATOMIC_ACQUIRE, __HIP_MEMORY_SCOPE_AGENT);
        }
      }
      __threadfence();  // acquire: invalidate stale L1/L2 before reading new h
    }
    __syncthreads();
  }
}

// ---------------- classifier from bf16 xcat ----------------
__global__ __launch_bounds__(256) void cls_kernel_bf(const ushort* __restrict__ x2,
                                                     const float* __restrict__ cw,
                                                     const float* __restrict__ cb,
                                                     float* __restrict__ em) {
  int idx = blockIdx.x * blockDim.x + threadIdx.x;
  if (idx >= BB * TT * LL) return;
  int l = idx % LL;
  int bt = idx / LL;
  int t = bt % TT;
  int b = bt / TT;
  const ushort* xr = x2 + ((size_t)t * BB + b) * 1024;
  const float* wr = cw + (size_t)l * 1024;
  float s = 0.f;
#pragma unroll 4
  for (int k = 0; k < 1024; k += 8) {
    uint4 xv = *(const uint4*)(xr + k);
    float4 wa = *(const float4*)(wr + k);
    float4 wb = *(const float4*)(wr + k + 4);
    s += bf2f(xv.x & 0xffffu) * wa.x + __uint_as_float(xv.x & 0xffff0000u) * wa.y;
    s += bf2f(xv.y & 0xffffu) * wa.z + __uint_as_float(xv.y & 0xffff0000u) * wa.w;
    s += bf2f(xv.z & 0xffffu) * wb.x + __uint_as_float(xv.z & 0xffff0000u) * wb.y;
    s += bf2f(xv.w & 0xffffu) * wb.z + __uint_as_float(xv.w & 0xffff0000u) * wb.w;
  }
  em[idx] = s + cb[l];
}

// ---------------- CRF NLL ----------------
__global__ __launch_bounds__(320) void crf_kernel(const float* __restrict__ em,
                                                  const int* __restrict__ labels,
                                                  const int* __restrict__ mask,
                                                  const float* __restrict__ start,
                                                  const float* __restrict__ end,
                                                  const float* __restrict__ trans,
                                                  float* __restrict__ loss_out) {
  __shared__ float al[32][9], tr[81], st[9], en[9];
  __shared__ float sc[32], red[32];
  __shared__ int pv[32];
  int tid = threadIdx.x;
  if (tid < 81) tr[tid] = trans[tid];
  if (tid < 9) { st[tid] = start[tid]; en[tid] = end[tid]; }
  __syncthreads();
  int j = tid >> 5, b = tid & 31;
  bool act = tid < 288;
  if (act) {
    int tg0 = labels[b * TT + 0];
    if (tg0 == -100) tg0 = 0;
    al[b][j] = st[j] + em[((size_t)b * TT + 0) * LL + j];
    if (j == 0) {
      sc[b] = st[tg0] + em[((size_t)b * TT + 0) * LL + tg0];
      pv[b] = tg0;
    }
  }
  __syncthreads();
  for (int t = 1; t < TT; t++) {
    float nxt = 0.f;
    int tg = 0;
    float mk = 0.f;
    if (act) {
      tg = labels[b * TT + t];
      if (tg == -100) tg = 0;
      mk = (float)mask[b * TT + t];
      float e_tj = em[((size_t)b * TT + t) * LL + j];
      float m = -1e30f;
#pragma unroll
      for (int i = 0; i < 9; i++) m = fmaxf(m, al[b][i] + tr[i * 9 + j]);
      float s = 0.f;
#pragma unroll
      for (int i = 0; i < 9; i++) s += expf(al[b][i] + tr[i * 9 + j] - m);
      nxt = m + logf(s) + e_tj;
    }
    __syncthreads();
    if (act) {
      if (j == 0 && mk > 0.f) {
        sc[b] += tr[pv[b] * 9 + tg] + em[((size_t)b * TT + t) * LL + tg];
      }
      if (mk > 0.f) al[b][j] = nxt;
      if (j == 0 && mk > 0.f) pv[b] = tg;
    }
    __syncthreads();
  }
  if (act && j == 0) {
    float m = -1e30f;
    for (int i = 0; i < 9; i++) m = fmaxf(m, al[b][i] + en[i]);
    float s = 0.f;
    for (int i = 0; i < 9; i++) s += expf(al[b][i] + en[i] - m);
    float logz = m + logf(s);
    red[b] = (sc[b] + en[pv[b]]) - logz;
  }
  __syncthreads();
  if (tid == 0) {
    float tot = 0.f;
    for (int bb = 0; bb < 32; bb++) tot += red[bb];
    loss_out[0] = -tot / 32.f;
  }
}

extern "C" void kernel_launch(void* const* d_in, const int* in_sizes, int n_in,
                              void* d_out, int out_size, void* d_ws, size_t ws_size,
                              hipStream_t stream) {
  (void)in_sizes; (void)n_in; (void)out_size; (void)ws_size;
  const int* ids = (const int*)d_in[0];
  const int* amask = (const int*)d_in[1];
  const int* labels = (const int*)d_in[2];
  const float* emb = (const float*)d_in[3];
  const float* wih0f = (const float*)d_in[4];
  const float* whh0f = (const float*)d_in[5];
  const float* bih0f = (const float*)d_in[6];
  const float* bhh0f = (const float*)d_in[7];
  const float* wih0r = (const float*)d_in[8];
  const float* whh0r = (const float*)d_in[9];
  const float* bih0r = (const float*)d_in[10];
  const float* bhh0r = (const float*)d_in[11];
  const float* wih1f = (const float*)d_in[12];
  const float* whh1f = (const float*)d_in[13];
  const float* bih1f = (const float*)d_in[14];
  const float* bhh1f = (const float*)d_in[15];
  const float* wih1r = (const float*)d_in[16];
  const float* whh1r = (const float*)d_in[17];
  const float* bih1r = (const float*)d_in[18];
  const float* bhh1r = (const float*)d_in[19];
  const float* cls_w = (const float*)d_in[20];
  const float* cls_b = (const float*)d_in[21];
  const float* crf_s = (const float*)d_in[22];
  const float* crf_e = (const float*)d_in[23];
  const float* crf_t = (const float*)d_in[24];

  char* base = (char*)d_ws;
  int* sync0 = (int*)base;                       // layer0 sync (4KB)
  int* sync1 = (int*)(base + 4096);              // layer1 sync (4KB)
  ushort* hA = (ushort*)(base + 8192);           // layer0 ping (zeroed)
  ushort* hC = hA + 32768;                       // layer1 ping (zeroed)
  ushort* hB = hC + 32768;                       // layer0 pong
  ushort* hD = hB + 32768;                       // layer1 pong
  ushort* xc_bf = hD + 32768;                    // (8192,1024) bf16
  ushort* x0bf = xc_bf + 8388608;                // (8192,256) bf16
  ushort* wihp0f = x0bf + 2097152;
  ushort* wihp0r = wihp0f + 524288;
  ushort* wihp1f = wihp0r + 524288;
  ushort* wihp1r = wihp1f + 2097152;
  ushort* whhp0f = wihp1r + 2097152;
  ushort* whhp0r = whhp0f + 1048576;
  ushort* whhp1f = whhp0r + 1048576;
  ushort* whhp1r = whhp1f + 1048576;
  float* pref = (float*)(whhp1r + 1048576);      // (8192,2048) f32
  float* prer = pref + 16777216;                 // total ~166 MB

  float* loss = (float*)d_out;
  float* em = (float*)d_out + 1;

  // zero: both sync areas + both ping h-buffers (contiguous 8KB + 128KB)
  hipMemsetAsync(d_ws, 0, 8192 + 131072, stream);

  embed_bf16<<<2048, 256, 0, stream>>>(ids, emb, x0bf);
  conv_perm_bf16<256><<<512, 256, 0, stream>>>(wih0f, wihp0f);
  conv_perm_bf16<256><<<512, 256, 0, stream>>>(wih0r, wihp0r);
  conv_perm_bf16<1024><<<2048, 256, 0, stream>>>(wih1f, wihp1f);
  conv_perm_bf16<1024><<<2048, 256, 0, stream>>>(wih1r, wihp1r);
  conv_perm_bf16<512><<<1024, 256, 0, stream>>>(whh0f, whhp0f);
  conv_perm_bf16<512><<<1024, 256, 0, stream>>>(whh0r, whhp0r);
  conv_perm_bf16<512><<<1024, 256, 0, stream>>>(whh1f, whhp1f);
  conv_perm_bf16<512><<<1024, 256, 0, stream>>>(whh1r, whhp1r);

  // ---- layer 0 ----
  pre_gemm_mfma<256><<<dim3(64, 16), 256, 0, stream>>>(x0bf, wihp0f, bih0f, bhh0f, pref);
  pre_gemm_mfma<256><<<dim3(64, 16), 256, 0, stream>>>(x0bf, wihp0r, bih0r, bhh0r, prer);
  {
    const float* a0 = pref; const float* a1 = prer;
    const ushort* a2 = whhp0f; const ushort* a3 = whhp0r;
    ushort* a4 = hA; ushort* a5 = hB;
    ushort* a6 = xc_bf; int* a7 = sync0;
    void* args[] = {&a0, &a1, &a2, &a3, &a4, &a5, &a6, &a7};
    hipLaunchCooperativeKernel((void*)lstm_layer_mfma, dim3(2 * NWGD), dim3(256), args, 0, stream);
  }
  // ---- layer 1 ----
  pre_gemm_mfma<1024><<<dim3(64, 16), 256, 0, stream>>>(xc_bf, wihp1f, bih1f, bhh1f, pref);
  pre_gemm_mfma<1024><<<dim3(64, 16), 256, 0, stream>>>(xc_bf, wihp1r, bih1r, bhh1r, prer);
  {
    const float* a0 = pref; const float* a1 = prer;
    const ushort* a2 = whhp1f; const ushort* a3 = whhp1r;
    ushort* a4 = hC; ushort* a5 = hD;
    ushort* a6 = xc_bf; int* a7 = sync1;
    void* args[] = {&a0, &a1, &a2, &a3, &a4, &a5, &a6, &a7};
    hipLaunchCooperativeKernel((void*)lstm_layer_mfma, dim3(2 * NWGD), dim3(256), args, 0, stream);
  }

  cls_kernel_bf<<<(BB * TT * LL + 255) / 256, 256, 0, stream>>>(xc_bf, cls_w, cls_b, em);
  crf_kernel<<<1, 320, 0, stream>>>(em, labels, amask, crf_s, crf_e, crf_t, loss);
}